// Round 2
// baseline (98.176 us; speedup 1.0000x reference)
//
#include <hip/hip_runtime.h>

// Problem constants (reference: B=8, E=16, H=256, W=256)
#define NB 8
#define NE 16
#define HW (256 * 256)        // pixels per sample = 65536
#define NPIX (NB * HW)        // total pixels = 524288

// val(pixel) = mean_e |f_e - o| - 0.5 * mean_{e,e'} |f_e - f_e'|
//            = (1/16) * S1 - (1/256) * S2   (S2 = sum over unordered pairs)
// out = (1/NPIX) * sum over pixels of val

__global__ __launch_bounds__(256) void crps_kernel(
    const float* __restrict__ fore,   // [B, E, HW]
    const float* __restrict__ obs,    // [B, HW]
    float* __restrict__ out)          // [1]
{
    const int tid = blockIdx.x * blockDim.x + threadIdx.x;   // 0 .. NPIX-1
    const int b = tid >> 16;            // tid / HW
    const int p = tid & (HW - 1);       // pixel within sample

    // 16 coalesced dword loads (64 lanes x 4B = 256B contiguous per instr).
    // 1 pixel/thread keeps VGPRs ~40 -> full 32 waves/CU occupancy
    // (2048 blocks = 8 blocks/CU), vs 8 waves/CU in the float4 version.
    float f[NE];
#pragma unroll
    for (int e = 0; e < NE; ++e)
        f[e] = fore[((size_t)(b * NE + e) << 16) + p];
    const float o = obs[((size_t)b << 16) + p];

    float s1 = 0.0f;
#pragma unroll
    for (int e = 0; e < NE; ++e)
        s1 += fabsf(f[e] - o);

    // Pairwise spread with 4 independent accumulators to break the serial
    // dependence chain (120 terms -> 4 chains of ~30).
    float s2a = 0.0f, s2b = 0.0f, s2c = 0.0f, s2d = 0.0f;
#pragma unroll
    for (int i = 0; i < NE; ++i) {
#pragma unroll
        for (int j = i + 1; j < NE; ++j) {
            float d = fabsf(f[i] - f[j]);
            int k = (i + j) & 3;
            if      (k == 0) s2a += d;
            else if (k == 1) s2b += d;
            else if (k == 2) s2c += d;
            else             s2d += d;
        }
    }
    float s2 = (s2a + s2b) + (s2c + s2d);

    float acc = s1 * (1.0f / NE) - s2 * (1.0f / (NE * NE));

    // Wave (64-lane) shuffle reduction
#pragma unroll
    for (int off = 32; off > 0; off >>= 1)
        acc += __shfl_down(acc, off);

    __shared__ float smem[4];           // 256 threads = 4 waves
    const int lane = threadIdx.x & 63;
    const int wave = threadIdx.x >> 6;
    if (lane == 0) smem[wave] = acc;
    __syncthreads();
    if (threadIdx.x == 0) {
        float s = smem[0] + smem[1] + smem[2] + smem[3];
        atomicAdd(out, s * (1.0f / NPIX));  // one device-scope atomic per block
    }
}

extern "C" void kernel_launch(void* const* d_in, const int* in_sizes, int n_in,
                              void* d_out, int out_size, void* d_ws, size_t ws_size,
                              hipStream_t stream) {
    const float* fore = (const float*)d_in[0];   // [8,16,256,256] f32
    const float* obs  = (const float*)d_in[1];   // [8,256,256] f32
    float* out = (float*)d_out;

    // d_out is re-poisoned to 0xAA before every timed launch — zero it.
    hipMemsetAsync(out, 0, sizeof(float), stream);

    const int threads = 256;
    const int blocks  = NPIX / threads;   // 524288 / 256 = 2048
    crps_kernel<<<blocks, threads, 0, stream>>>(fore, obs, out);
}

// Round 3
// 77.309 us; speedup vs baseline: 1.2699x; 1.2699x over previous
//
#include <hip/hip_runtime.h>

// Problem constants (reference: B=8, E=16, H=256, W=256)
#define NB 8
#define NE 16
#define HW (256 * 256)        // pixels per sample = 65536
#define HW4 (HW / 4)          // float4 groups per sample = 16384
#define NPIX (NB * HW)        // total pixels = 524288
#define NT4 (NPIX / 4)        // total float4 pixel-groups = 131072
#define NBLK 512              // K1 grid (NT4 / 256)

// val(pixel) = mean_e |f_e - o| - 0.5 * mean_{e,e'} |f_e - f_e'|
//            = (1/16) * S1 - (1/256) * S2   (S2 = unordered-pair sum)
// out = (1/NPIX) * sum over pixels of val
//
// Two-kernel deterministic reduction: K1 writes one plain partial per block
// to d_ws (no zero-init needed, no atomics — 512 same-address atomicAdds
// serialized at the TCC and cost ~5-20us in R1/R2), K2 sums the partials.

__global__ __launch_bounds__(256) void crps_partial_kernel(
    const float* __restrict__ fore,   // [B, E, HW]
    const float* __restrict__ obs,    // [B, HW]
    float* __restrict__ partial)      // [NBLK]
{
    const int idx = blockIdx.x * blockDim.x + threadIdx.x;   // 0 .. NT4-1
    const int b  = idx >> 14;          // idx / HW4
    const int p4 = idx & (HW4 - 1);

    const float4* fore4 = reinterpret_cast<const float4*>(fore);
    const float4* obs4  = reinterpret_cast<const float4*>(obs);

    // 16 ensemble members, 16B/lane coalesced loads (1KB per wave-instr).
    // All 17 loads issue before first use -> ~17KB in flight per wave,
    // ample MLP at 8 waves/CU to cover ~900cyc HBM latency.
    float v[NE][4];
#pragma unroll
    for (int e = 0; e < NE; ++e) {
        float4 t = fore4[(size_t)(b * NE + e) * HW4 + p4];
        v[e][0] = t.x; v[e][1] = t.y; v[e][2] = t.z; v[e][3] = t.w;
    }
    float4 ot = obs4[(size_t)b * HW4 + p4];
    float o[4] = { ot.x, ot.y, ot.z, ot.w };

    // 4 components are independent -> 4-way ILP on the add chains.
    float acc = 0.0f;
#pragma unroll
    for (int c = 0; c < 4; ++c) {
        float s1 = 0.0f;
#pragma unroll
        for (int e = 0; e < NE; ++e)
            s1 += fabsf(v[e][c] - o[c]);
        float s2 = 0.0f;
#pragma unroll
        for (int i = 0; i < NE; ++i)
#pragma unroll
            for (int j = i + 1; j < NE; ++j)
                s2 += fabsf(v[i][c] - v[j][c]);
        acc += s1 * (1.0f / NE) - s2 * (1.0f / (NE * NE));
    }

    // Wave (64-lane) shuffle reduction
#pragma unroll
    for (int off = 32; off > 0; off >>= 1)
        acc += __shfl_down(acc, off);

    __shared__ float smem[4];          // 256 threads = 4 waves
    const int lane = threadIdx.x & 63;
    const int wave = threadIdx.x >> 6;
    if (lane == 0) smem[wave] = acc;
    __syncthreads();
    if (threadIdx.x == 0)
        partial[blockIdx.x] = smem[0] + smem[1] + smem[2] + smem[3];
}

__global__ __launch_bounds__(256) void crps_final_kernel(
    const float* __restrict__ partial,  // [NBLK]
    float* __restrict__ out)            // [1]
{
    const int t = threadIdx.x;
    float acc = partial[t] + partial[t + 256];   // 512 partials, 256 threads

#pragma unroll
    for (int off = 32; off > 0; off >>= 1)
        acc += __shfl_down(acc, off);

    __shared__ float smem[4];
    const int lane = t & 63;
    const int wave = t >> 6;
    if (lane == 0) smem[wave] = acc;
    __syncthreads();
    if (t == 0)
        out[0] = (smem[0] + smem[1] + smem[2] + smem[3]) * (1.0f / NPIX);
}

extern "C" void kernel_launch(void* const* d_in, const int* in_sizes, int n_in,
                              void* d_out, int out_size, void* d_ws, size_t ws_size,
                              hipStream_t stream) {
    const float* fore = (const float*)d_in[0];   // [8,16,256,256] f32
    const float* obs  = (const float*)d_in[1];   // [8,256,256] f32
    float* out     = (float*)d_out;
    float* partial = (float*)d_ws;               // 512 floats of scratch

    crps_partial_kernel<<<NBLK, 256, 0, stream>>>(fore, obs, partial);
    crps_final_kernel<<<1, 256, 0, stream>>>(partial, out);
}